// Round 1
// baseline (654.531 us; speedup 1.0000x reference)
//
#include <hip/hip_runtime.h>
#include <math.h>

#define NEG_SLOPE 0.2f

// ---------------- degree / normalization ----------------
__global__ void k_deg_init(float* __restrict__ deg, int n) {
    int i = blockIdx.x * 256 + threadIdx.x;
    if (i < n) deg[i] = 1.0f;  // self-loop
}

__global__ void k_deg_count(const int* __restrict__ dst, float* __restrict__ deg, int e) {
    int i = blockIdx.x * 256 + threadIdx.x;
    if (i < e) atomicAdd(&deg[dst[i]], 1.0f);
}

__global__ void k_deg_finish(float* __restrict__ deg, int n) {
    int i = blockIdx.x * 256 + threadIdx.x;
    if (i < n) deg[i] = 1.0f / sqrtf(deg[i]);
}

// ---------------- GEMM: [n,64] @ [64,64] -> [n,64] ----------------
__global__ void k_gemm64(const float* __restrict__ in, const float* __restrict__ W,
                         float* __restrict__ out, int n) {
    __shared__ float Ws[64 * 64];
    __shared__ float Xs[4 * 64];
    int t = threadIdx.x;  // 256 threads
    for (int i = t; i < 64 * 64; i += 256) Ws[i] = W[i];
    int r = t >> 6, c = t & 63;
    int row = blockIdx.x * 4 + r;
    if (row < n) Xs[t] = in[row * 64 + c];
    __syncthreads();
    if (row < n) {
        float acc = 0.0f;
#pragma unroll
        for (int k = 0; k < 64; ++k) acc = fmaf(Xs[r * 64 + k], Ws[k * 64 + c], acc);
        out[row * 64 + c] = acc;
    }
}

// ---------------- GEMM: [n,64] @ [64,4] -> [n,4] ----------------
__global__ void k_gemm4(const float* __restrict__ in, const float* __restrict__ W,
                        float* __restrict__ out, int n) {
    __shared__ float Ws[64 * 4];
    int t = threadIdx.x;
    if (t < 256) Ws[t] = W[t];
    __syncthreads();
    int row = blockIdx.x * 256 + t;
    if (row >= n) return;
    float a0 = 0.f, a1 = 0.f, a2 = 0.f, a3 = 0.f;
#pragma unroll
    for (int k = 0; k < 64; ++k) {
        float x = in[row * 64 + k];
        a0 = fmaf(x, Ws[k * 4 + 0], a0);
        a1 = fmaf(x, Ws[k * 4 + 1], a1);
        a2 = fmaf(x, Ws[k * 4 + 2], a2);
        a3 = fmaf(x, Ws[k * 4 + 3], a3);
    }
    float4 o = make_float4(a0, a1, a2, a3);
    *reinterpret_cast<float4*>(out + row * 4) = o;
}

// ---------------- acc init: self-loop + bias ----------------
__global__ void k_init64(const float* __restrict__ h, const float* __restrict__ dinv,
                         const float* __restrict__ b, float* __restrict__ acc, int n) {
    int idx = blockIdx.x * 256 + threadIdx.x;
    if (idx >= n * 64) return;
    int row = idx >> 6, c = idx & 63;
    float dv = dinv[row];
    acc[idx] = h[idx] * dv * dv + b[c];
}

__global__ void k_init4(const float* __restrict__ h, const float* __restrict__ dinv,
                        const float* __restrict__ b, float* __restrict__ acc, int n) {
    int idx = blockIdx.x * 256 + threadIdx.x;
    if (idx >= n * 4) return;
    int row = idx >> 2, c = idx & 3;
    float dv = dinv[row];
    acc[idx] = h[idx] * dv * dv + b[c];
}

// ---------------- edge scatter: wave per edge, lane = channel ----------------
__global__ void k_scatter64(const float* __restrict__ h, const float* __restrict__ dinv,
                            const int* __restrict__ src, const int* __restrict__ dst,
                            float* __restrict__ acc, int nedges) {
    int gid = blockIdx.x * blockDim.x + threadIdx.x;
    int wave = gid >> 6;
    int lane = threadIdx.x & 63;
    int nwaves = (gridDim.x * blockDim.x) >> 6;
    for (int e = wave; e < nedges; e += nwaves) {
        int s = src[e], d = dst[e];
        float norm = dinv[s] * dinv[d];
        float v = h[s * 64 + lane] * norm;
        atomicAdd(&acc[d * 64 + lane], v);
    }
}

__global__ void k_scatter4(const float* __restrict__ h, const float* __restrict__ dinv,
                           const int* __restrict__ src, const int* __restrict__ dst,
                           float* __restrict__ acc, int nedges) {
    int e = blockIdx.x * 256 + threadIdx.x;
    if (e >= nedges) return;
    int s = src[e], d = dst[e];
    float norm = dinv[s] * dinv[d];
    float4 v = *reinterpret_cast<const float4*>(h + s * 4);
    atomicAdd(&acc[d * 4 + 0], v.x * norm);
    atomicAdd(&acc[d * 4 + 1], v.y * norm);
    atomicAdd(&acc[d * 4 + 2], v.z * norm);
    atomicAdd(&acc[d * 4 + 3], v.w * norm);
}

// ---------------- leaky relu in place ----------------
__global__ void k_act64(float* __restrict__ a, int n64) {
    int idx = blockIdx.x * 256 + threadIdx.x;
    if (idx >= n64) return;
    float v = a[idx];
    a[idx] = v > 0.0f ? v : NEG_SLOPE * v;
}

extern "C" void kernel_launch(void* const* d_in, const int* in_sizes, int n_in,
                              void* d_out, int out_size, void* d_ws, size_t ws_size,
                              hipStream_t stream) {
    const float* x  = (const float*)d_in[0];
    const int* ei   = (const int*)d_in[1];
    const float* W0 = (const float*)d_in[2];
    const float* b0 = (const float*)d_in[3];
    const float* W1 = (const float*)d_in[4];
    const float* b1 = (const float*)d_in[5];
    const float* W2 = (const float*)d_in[6];
    const float* b2 = (const float*)d_in[7];
    float* out = (float*)d_out;

    const int N = in_sizes[0] / 64;
    const int E = in_sizes[1] / 2;
    const int* src = ei;
    const int* dst = ei + E;

    float* dinv = (float*)d_ws;            // N floats (deg then dinv, in place)
    float* bufA = dinv + 50176;            // N*64: h_pre
    float* bufB = bufA + (size_t)N * 64;   // N*64: acc / activated h

    const int nb_N   = (N + 255) / 256;
    const int nb_E   = (E + 255) / 256;
    const int nb_N64 = (N * 64 + 255) / 256;

    // normalization
    k_deg_init<<<nb_N, 256, 0, stream>>>(dinv, N);
    k_deg_count<<<nb_E, 256, 0, stream>>>(dst, dinv, E);
    k_deg_finish<<<nb_N, 256, 0, stream>>>(dinv, N);

    // ---- layer 0 ----
    k_gemm64<<<(N + 3) / 4, 256, 0, stream>>>(x, W0, bufA, N);
    k_init64<<<nb_N64, 256, 0, stream>>>(bufA, dinv, b0, bufB, N);
    k_scatter64<<<4096, 256, 0, stream>>>(bufA, dinv, src, dst, bufB, E);
    k_act64<<<nb_N64, 256, 0, stream>>>(bufB, N * 64);

    // ---- layer 1 ----
    k_gemm64<<<(N + 3) / 4, 256, 0, stream>>>(bufB, W1, bufA, N);
    k_init64<<<nb_N64, 256, 0, stream>>>(bufA, dinv, b1, bufB, N);
    k_scatter64<<<4096, 256, 0, stream>>>(bufA, dinv, src, dst, bufB, E);
    k_act64<<<nb_N64, 256, 0, stream>>>(bufB, N * 64);

    // ---- layer 2 (d_out = 4) ----
    k_gemm4<<<(N + 255) / 256, 256, 0, stream>>>(bufB, W2, bufA, N);
    k_init4<<<(N * 4 + 255) / 256, 256, 0, stream>>>(bufA, dinv, b2, out, N);
    k_scatter4<<<nb_E, 256, 0, stream>>>(bufA, dinv, src, dst, out, E);
}

// Round 2
// 396.412 us; speedup vs baseline: 1.6511x; 1.6511x over previous
//
#include <hip/hip_runtime.h>
#include <math.h>

#define NEG_SLOPE 0.2f

// ---------------- CSR build ----------------
__global__ void k_count(const int* __restrict__ dst, int* __restrict__ cnt, int e) {
    int i = blockIdx.x * 256 + threadIdx.x;
    if (i < e) atomicAdd(&cnt[dst[i]], 1);
}

__global__ void k_dinv(const int* __restrict__ cnt, float* __restrict__ dinv, int n) {
    int i = blockIdx.x * 256 + threadIdx.x;
    if (i < n) dinv[i] = 1.0f / sqrtf((float)(cnt[i] + 1));  // +1 self-loop
}

// single-block exclusive scan of cnt[0..n) -> rowptr[0..n]
__global__ void k_scan(const int* __restrict__ cnt, int* __restrict__ rowptr, int n) {
    __shared__ int lsum[1024];
    int t = threadIdx.x;
    int chunk = (n + 1023) >> 10;
    int start = t * chunk;
    int end = min(start + chunk, n);
    int s = 0;
    for (int i = start; i < end; ++i) s += cnt[i];
    lsum[t] = s;
    __syncthreads();
    for (int d = 1; d < 1024; d <<= 1) {
        int v = (t >= d) ? lsum[t - d] : 0;
        __syncthreads();
        lsum[t] += v;
        __syncthreads();
    }
    int off = lsum[t] - s;  // exclusive
    for (int i = start; i < end; ++i) { rowptr[i] = off; off += cnt[i]; }
    if (end == n) rowptr[n] = off;
}

__global__ void k_fill(const int* __restrict__ src, const int* __restrict__ dst,
                       const float* __restrict__ dinv, const int* __restrict__ rowptr,
                       int* __restrict__ cursor, int* __restrict__ perm,
                       float* __restrict__ nrm, int e) {
    int i = blockIdx.x * 256 + threadIdx.x;
    if (i >= e) return;
    int s = src[i], d = dst[i];
    int slot = rowptr[d] + atomicAdd(&cursor[d], 1);
    perm[slot] = s;
    nrm[slot] = dinv[s] * dinv[d];
}

// ---------------- GEMM: [n,64] @ [64,64] -> [n,64] ----------------
__global__ void k_gemm64(const float* __restrict__ in, const float* __restrict__ W,
                         float* __restrict__ out, int n) {
    __shared__ float Ws[64 * 64];
    __shared__ float Xs[4 * 64];
    int t = threadIdx.x;  // 256 threads
    for (int i = t; i < 64 * 64; i += 256) Ws[i] = W[i];
    int r = t >> 6, c = t & 63;
    int row = blockIdx.x * 4 + r;
    if (row < n) Xs[t] = in[row * 64 + c];
    __syncthreads();
    if (row < n) {
        float acc = 0.0f;
#pragma unroll
        for (int k = 0; k < 64; ++k) acc = fmaf(Xs[r * 64 + k], Ws[k * 64 + c], acc);
        out[row * 64 + c] = acc;
    }
}

// ---------------- GEMM: [n,64] @ [64,4] -> [n,4] ----------------
__global__ void k_gemm4(const float* __restrict__ in, const float* __restrict__ W,
                        float* __restrict__ out, int n) {
    __shared__ float Ws[64 * 4];
    int t = threadIdx.x;
    if (t < 256) Ws[t] = W[t];
    __syncthreads();
    int row = blockIdx.x * 256 + t;
    if (row >= n) return;
    float a0 = 0.f, a1 = 0.f, a2 = 0.f, a3 = 0.f;
#pragma unroll
    for (int k = 0; k < 64; ++k) {
        float x = in[row * 64 + k];
        a0 = fmaf(x, Ws[k * 4 + 0], a0);
        a1 = fmaf(x, Ws[k * 4 + 1], a1);
        a2 = fmaf(x, Ws[k * 4 + 2], a2);
        a3 = fmaf(x, Ws[k * 4 + 3], a3);
    }
    *reinterpret_cast<float4*>(out + row * 4) = make_float4(a0, a1, a2, a3);
}

// ---------------- gather: wave per node, lane = channel; fuses self-loop+bias+act ----------------
__global__ void k_gather64(const float* __restrict__ h, const float* __restrict__ dinv,
                           const int* __restrict__ rowptr, const int* __restrict__ perm,
                           const float* __restrict__ nrm, const float* __restrict__ b,
                           float* __restrict__ out, int n, int act) {
    int t = threadIdx.x;
    int v = blockIdx.x * 4 + (t >> 6);
    int lane = t & 63;
    if (v >= n) return;
    float dv = dinv[v];
    float acc = h[v * 64 + lane] * dv * dv + b[lane];
    int beg = rowptr[v], end = rowptr[v + 1];
    for (int e = beg; e < end; ++e) {
        int s = perm[e];
        float w = nrm[e];
        acc = fmaf(h[s * 64 + lane], w, acc);
    }
    if (act) acc = acc > 0.0f ? acc : NEG_SLOPE * acc;
    out[v * 64 + lane] = acc;
}

// ---------------- gather for d=4 output: thread per node ----------------
__global__ void k_gather4(const float* __restrict__ h, const float* __restrict__ dinv,
                          const int* __restrict__ rowptr, const int* __restrict__ perm,
                          const float* __restrict__ nrm, const float* __restrict__ b,
                          float* __restrict__ out, int n) {
    int v = blockIdx.x * 256 + threadIdx.x;
    if (v >= n) return;
    float dv = dinv[v];
    float4 hv = *reinterpret_cast<const float4*>(h + v * 4);
    float s2 = dv * dv;
    float a0 = hv.x * s2 + b[0];
    float a1 = hv.y * s2 + b[1];
    float a2 = hv.z * s2 + b[2];
    float a3 = hv.w * s2 + b[3];
    int beg = rowptr[v], end = rowptr[v + 1];
    for (int e = beg; e < end; ++e) {
        int s = perm[e];
        float w = nrm[e];
        float4 hs = *reinterpret_cast<const float4*>(h + s * 4);
        a0 = fmaf(hs.x, w, a0);
        a1 = fmaf(hs.y, w, a1);
        a2 = fmaf(hs.z, w, a2);
        a3 = fmaf(hs.w, w, a3);
    }
    *reinterpret_cast<float4*>(out + v * 4) = make_float4(a0, a1, a2, a3);
}

extern "C" void kernel_launch(void* const* d_in, const int* in_sizes, int n_in,
                              void* d_out, int out_size, void* d_ws, size_t ws_size,
                              hipStream_t stream) {
    const float* x  = (const float*)d_in[0];
    const int* ei   = (const int*)d_in[1];
    const float* W0 = (const float*)d_in[2];
    const float* b0 = (const float*)d_in[3];
    const float* W1 = (const float*)d_in[4];
    const float* b1 = (const float*)d_in[5];
    const float* W2 = (const float*)d_in[6];
    const float* b2 = (const float*)d_in[7];
    float* out = (float*)d_out;

    const int N = in_sizes[0] / 64;
    const int E = in_sizes[1] / 2;
    const int* src = ei;
    const int* dst = ei + E;

    // workspace layout (4B elements, padded to keep 16B alignment)
    const size_t PAD_N = 50176;
    float* base = (float*)d_ws;
    int*   cnt    = (int*)base;                      // PAD_N
    float* dinv   = base + PAD_N;                    // PAD_N
    int*   rowptr = (int*)(base + 2 * PAD_N);        // PAD_N (N+1 used)
    int*   cursor = (int*)(base + 3 * PAD_N);        // PAD_N
    int*   perm   = (int*)(base + 4 * PAD_N);        // E
    float* nrm    = base + 4 * PAD_N + (size_t)E;    // E
    float* bufA   = base + 4 * PAD_N + 2 * (size_t)E;
    float* bufB   = bufA + (size_t)N * 64;

    const int nb_N   = (N + 255) / 256;
    const int nb_E   = (E + 255) / 256;

    // ---- CSR build + normalization ----
    hipMemsetAsync(cnt, 0, PAD_N * sizeof(int), stream);
    hipMemsetAsync(cursor, 0, PAD_N * sizeof(int), stream);
    k_count<<<nb_E, 256, 0, stream>>>(dst, cnt, E);
    k_dinv<<<nb_N, 256, 0, stream>>>(cnt, dinv, N);
    k_scan<<<1, 1024, 0, stream>>>(cnt, rowptr, N);
    k_fill<<<nb_E, 256, 0, stream>>>(src, dst, dinv, rowptr, cursor, perm, nrm, E);

    // ---- layer 0 ----
    k_gemm64<<<(N + 3) / 4, 256, 0, stream>>>(x, W0, bufA, N);
    k_gather64<<<(N + 3) / 4, 256, 0, stream>>>(bufA, dinv, rowptr, perm, nrm, b0, bufB, N, 1);

    // ---- layer 1 ----
    k_gemm64<<<(N + 3) / 4, 256, 0, stream>>>(bufB, W1, bufA, N);
    k_gather64<<<(N + 3) / 4, 256, 0, stream>>>(bufA, dinv, rowptr, perm, nrm, b1, bufB, N, 1);

    // ---- layer 2 (d_out = 4) ----
    k_gemm4<<<nb_N, 256, 0, stream>>>(bufB, W2, bufA, N);
    k_gather4<<<nb_N, 256, 0, stream>>>(bufA, dinv, rowptr, perm, nrm, b2, out, N);
}

// Round 3
// 300.786 us; speedup vs baseline: 2.1761x; 1.3179x over previous
//
#include <hip/hip_runtime.h>
#include <math.h>

#define NEG_SLOPE 0.2f

// ---------------- CSR build ----------------
__global__ void k_count(const int* __restrict__ dst, int* __restrict__ cnt, int e) {
    int i = blockIdx.x * 256 + threadIdx.x;
    if (i < e) atomicAdd(&cnt[dst[i]], 1);
}

__global__ void k_dinv(const int* __restrict__ cnt, float* __restrict__ dinv, int n) {
    int i = blockIdx.x * 256 + threadIdx.x;
    if (i < n) dinv[i] = rsqrtf((float)(cnt[i] + 1));  // +1 self-loop
}

// single-block exclusive scan of cnt[0..n) -> rowptr[0..n]
__global__ void k_scan(const int* __restrict__ cnt, int* __restrict__ rowptr, int n) {
    __shared__ int lsum[1024];
    int t = threadIdx.x;
    int chunk = (n + 1023) >> 10;
    int start = t * chunk;
    int end = min(start + chunk, n);
    int s = 0;
    for (int i = start; i < end; ++i) s += cnt[i];
    lsum[t] = s;
    __syncthreads();
    for (int d = 1; d < 1024; d <<= 1) {
        int v = (t >= d) ? lsum[t - d] : 0;
        __syncthreads();
        lsum[t] += v;
        __syncthreads();
    }
    int off = lsum[t] - s;  // exclusive
    for (int i = start; i < end; ++i) { rowptr[i] = off; off += cnt[i]; }
    if (end == n && start <= n) rowptr[n] = off;
}

// fill: slot via atomicSub on cnt (destroys cnt; bucket order irrelevant for a sum)
__global__ void k_fill(const int* __restrict__ src, const int* __restrict__ dst,
                       const int* __restrict__ rowptr, int* __restrict__ cnt,
                       int* __restrict__ perm, int e) {
    int i = blockIdx.x * 256 + threadIdx.x;
    if (i >= e) return;
    int d = dst[i];
    int slot = rowptr[d] + atomicSub(&cnt[d], 1) - 1;
    perm[slot] = src[i];
}

// ---------------- GEMM: [n,64] @ [64,64], epilogue * dinv[row] ----------------
__global__ __launch_bounds__(256) void k_gemm64(const float* __restrict__ in,
                                                const float* __restrict__ W,
                                                const float* __restrict__ dinv,
                                                float* __restrict__ out, int n) {
    __shared__ float Ws[64 * 64];
    __shared__ float Xs[16 * 64];
    int t = threadIdx.x;
    const float4* W4 = (const float4*)W;
    float4* Ws4 = (float4*)Ws;
#pragma unroll
    for (int i = 0; i < 4; ++i) Ws4[t + 256 * i] = W4[t + 256 * i];
    int row0 = blockIdx.x * 16;
    {
        int r = t >> 4, c4 = t & 15;
        int row = row0 + r;
        float4 v = make_float4(0.f, 0.f, 0.f, 0.f);
        if (row < n) v = ((const float4*)(in + (size_t)row * 64))[c4];
        ((float4*)Xs)[t] = v;
    }
    __syncthreads();
    int c = t & 63, g = t >> 6;
    float a0 = 0.f, a1 = 0.f, a2 = 0.f, a3 = 0.f;
#pragma unroll
    for (int k = 0; k < 64; ++k) {
        float w = Ws[k * 64 + c];
        a0 = fmaf(Xs[g * 64 + k], w, a0);
        a1 = fmaf(Xs[(g + 4) * 64 + k], w, a1);
        a2 = fmaf(Xs[(g + 8) * 64 + k], w, a2);
        a3 = fmaf(Xs[(g + 12) * 64 + k], w, a3);
    }
    int r;
    r = row0 + g;      if (r < n) out[(size_t)r * 64 + c] = a0 * dinv[r];
    r = row0 + g + 4;  if (r < n) out[(size_t)r * 64 + c] = a1 * dinv[r];
    r = row0 + g + 8;  if (r < n) out[(size_t)r * 64 + c] = a2 * dinv[r];
    r = row0 + g + 12; if (r < n) out[(size_t)r * 64 + c] = a3 * dinv[r];
}

// ---------------- GEMM: [n,64] @ [64,4], epilogue * dinv[row] ----------------
__global__ void k_gemm4(const float* __restrict__ in, const float* __restrict__ W,
                        const float* __restrict__ dinv, float* __restrict__ out, int n) {
    __shared__ float Ws[64 * 4];
    int t = threadIdx.x;
    Ws[t] = W[t];
    __syncthreads();
    int row = blockIdx.x * 256 + t;
    if (row >= n) return;
    float a0 = 0.f, a1 = 0.f, a2 = 0.f, a3 = 0.f;
    const float4* xin = (const float4*)(in + (size_t)row * 64);
#pragma unroll
    for (int k4 = 0; k4 < 16; ++k4) {
        float4 x = xin[k4];
        int k = k4 * 4;
        a0 = fmaf(x.x, Ws[k * 4 + 0], a0); a1 = fmaf(x.x, Ws[k * 4 + 1], a1);
        a2 = fmaf(x.x, Ws[k * 4 + 2], a2); a3 = fmaf(x.x, Ws[k * 4 + 3], a3);
        a0 = fmaf(x.y, Ws[k * 4 + 4], a0); a1 = fmaf(x.y, Ws[k * 4 + 5], a1);
        a2 = fmaf(x.y, Ws[k * 4 + 6], a2); a3 = fmaf(x.y, Ws[k * 4 + 7], a3);
        a0 = fmaf(x.z, Ws[k * 4 + 8], a0); a1 = fmaf(x.z, Ws[k * 4 + 9], a1);
        a2 = fmaf(x.z, Ws[k * 4 + 10], a2); a3 = fmaf(x.z, Ws[k * 4 + 11], a3);
        a0 = fmaf(x.w, Ws[k * 4 + 12], a0); a1 = fmaf(x.w, Ws[k * 4 + 13], a1);
        a2 = fmaf(x.w, Ws[k * 4 + 14], a2); a3 = fmaf(x.w, Ws[k * 4 + 15], a3);
    }
    float dv = dinv[row];
    *reinterpret_cast<float4*>(out + (size_t)row * 4) =
        make_float4(a0 * dv, a1 * dv, a2 * dv, a3 * dv);
}

// ---------------- gather 64ch: wave per node, lane = channel, unroll 8 ----------------
__global__ __launch_bounds__(256) void k_gather64(
        const float* __restrict__ h, const float* __restrict__ dinv,
        const int* __restrict__ rowptr, const int* __restrict__ perm,
        const float* __restrict__ b, float* __restrict__ out, int n, int act) {
    int t = threadIdx.x;
    int v = blockIdx.x * 4 + (t >> 6);
    if (v >= n) return;
    v = __builtin_amdgcn_readfirstlane(v);  // force SGPR: perm/rowptr become scalar loads
    int lane = t & 63;
    const float* hl = h + lane;
    float acc = hl[(size_t)v * 64];
    int e = rowptr[v], end = rowptr[v + 1];
#define LOADK(j) float x##j = hl[(size_t)perm[e + j] * 64]
    for (; e + 8 <= end; e += 8) {
        LOADK(0); LOADK(1); LOADK(2); LOADK(3);
        LOADK(4); LOADK(5); LOADK(6); LOADK(7);
        acc += ((x0 + x1) + (x2 + x3)) + ((x4 + x5) + (x6 + x7));
    }
    if (e + 4 <= end) {
        LOADK(0); LOADK(1); LOADK(2); LOADK(3);
        acc += (x0 + x1) + (x2 + x3);
        e += 4;
    }
    if (e + 2 <= end) {
        LOADK(0); LOADK(1);
        acc += x0 + x1;
        e += 2;
    }
    if (e < end) acc += hl[(size_t)perm[e] * 64];
#undef LOADK
    acc = acc * dinv[v] + b[lane];
    if (act) acc = acc > 0.0f ? acc : acc * NEG_SLOPE;
    out[(size_t)v * 64 + lane] = acc;
}

// ---------------- gather 4ch: 4 lanes per node, unroll 4 ----------------
__global__ __launch_bounds__(256) void k_gather4(
        const float* __restrict__ h, const float* __restrict__ dinv,
        const int* __restrict__ rowptr, const int* __restrict__ perm,
        const float* __restrict__ b, float* __restrict__ out, int n) {
    int gid = blockIdx.x * 256 + threadIdx.x;
    int c = gid & 3;
    int v = gid >> 2;
    if (v >= n) return;
    const float* hc = h + c;
    float acc = hc[(size_t)v * 4];
    int e = rowptr[v], end = rowptr[v + 1];
    for (; e + 4 <= end; e += 4) {
        float x0 = hc[(size_t)perm[e] * 4];
        float x1 = hc[(size_t)perm[e + 1] * 4];
        float x2 = hc[(size_t)perm[e + 2] * 4];
        float x3 = hc[(size_t)perm[e + 3] * 4];
        acc += (x0 + x1) + (x2 + x3);
    }
    for (; e < end; ++e) acc += hc[(size_t)perm[e] * 4];
    out[(size_t)v * 4 + c] = acc * dinv[v] + b[c];
}

extern "C" void kernel_launch(void* const* d_in, const int* in_sizes, int n_in,
                              void* d_out, int out_size, void* d_ws, size_t ws_size,
                              hipStream_t stream) {
    const float* x  = (const float*)d_in[0];
    const int* ei   = (const int*)d_in[1];
    const float* W0 = (const float*)d_in[2];
    const float* b0 = (const float*)d_in[3];
    const float* W1 = (const float*)d_in[4];
    const float* b1 = (const float*)d_in[5];
    const float* W2 = (const float*)d_in[6];
    const float* b2 = (const float*)d_in[7];
    float* out = (float*)d_out;

    const int N = in_sizes[0] / 64;
    const int E = in_sizes[1] / 2;
    const int* src = ei;
    const int* dst = ei + E;

    // workspace layout
    const size_t PAD_N = 50176;
    float* base = (float*)d_ws;
    int*   cnt    = (int*)base;                       // PAD_N
    float* dinv   = base + PAD_N;                     // PAD_N
    int*   rowptr = (int*)(base + 2 * PAD_N);         // N+1
    int*   perm   = (int*)(base + 3 * PAD_N);         // E
    float* bufA   = base + 3 * PAD_N + (size_t)E;     // N*64
    float* bufB   = bufA + (size_t)N * 64;            // N*64

    const int nb_N = (N + 255) / 256;
    const int nb_E = (E + 255) / 256;

    // ---- CSR build + normalization ----
    hipMemsetAsync(cnt, 0, PAD_N * sizeof(int), stream);
    k_count<<<nb_E, 256, 0, stream>>>(dst, cnt, E);
    k_dinv<<<nb_N, 256, 0, stream>>>(cnt, dinv, N);
    k_scan<<<1, 1024, 0, stream>>>(cnt, rowptr, N);
    k_fill<<<nb_E, 256, 0, stream>>>(src, dst, rowptr, cnt, perm, E);

    // ---- layer 0 ----
    k_gemm64<<<(N + 15) / 16, 256, 0, stream>>>(x, W0, dinv, bufA, N);
    k_gather64<<<(N + 3) / 4, 256, 0, stream>>>(bufA, dinv, rowptr, perm, b0, bufB, N, 1);

    // ---- layer 1 ----
    k_gemm64<<<(N + 15) / 16, 256, 0, stream>>>(bufB, W1, dinv, bufA, N);
    k_gather64<<<(N + 3) / 4, 256, 0, stream>>>(bufA, dinv, rowptr, perm, b1, bufB, N, 1);

    // ---- layer 2 (d_out = 4) ----
    k_gemm4<<<nb_N, 256, 0, stream>>>(bufB, W2, dinv, bufA, N);
    k_gather4<<<(N * 4 + 255) / 256, 256, 0, stream>>>(bufA, dinv, rowptr, perm, b2, out, N);
}

// Round 4
// 230.748 us; speedup vs baseline: 2.8366x; 1.3035x over previous
//
#include <hip/hip_runtime.h>
#include <math.h>

#define NEG_SLOPE 0.2f

// ---------------- CSR build ----------------
__global__ void k_count(const int* __restrict__ dst, int* __restrict__ cnt, int e) {
    int i = blockIdx.x * 256 + threadIdx.x;
    if (i < e) atomicAdd(&cnt[dst[i]], 1);
}

// phase 1: per-block(256) sums of cnt -> bsum; also dinv = rsqrt(cnt+1)
__global__ __launch_bounds__(256) void k_scan1(const int* __restrict__ cnt,
                                               int* __restrict__ bsum,
                                               float* __restrict__ dinv, int n) {
    int t = threadIdx.x;
    int i = blockIdx.x * 256 + t;
    int v = (i < n) ? cnt[i] : 0;
    if (i < n) dinv[i] = rsqrtf((float)(v + 1));  // +1 self-loop
    int s = v;
    for (int d = 1; d < 64; d <<= 1) s += __shfl_down(s, d);
    __shared__ int ws[4];
    if ((t & 63) == 0) ws[t >> 6] = s;
    __syncthreads();
    if (t == 0) bsum[blockIdx.x] = ws[0] + ws[1] + ws[2] + ws[3];
}

// phase 2: single-block exclusive scan of bsum[0..nb) (nb <= 256)
__global__ __launch_bounds__(256) void k_scan2(int* __restrict__ bsum, int nb) {
    __shared__ int ls[256];
    int t = threadIdx.x;
    int v = (t < nb) ? bsum[t] : 0;
    ls[t] = v;
    __syncthreads();
    for (int d = 1; d < 256; d <<= 1) {
        int u = (t >= d) ? ls[t - d] : 0;
        __syncthreads();
        ls[t] += u;
        __syncthreads();
    }
    if (t < nb) bsum[t] = ls[t] - v;  // exclusive
}

// phase 3: per-block scan + offset -> rowptr[0..n]
__global__ __launch_bounds__(256) void k_scan3(const int* __restrict__ cnt,
                                               const int* __restrict__ bsum,
                                               int* __restrict__ rowptr, int n) {
    __shared__ int ls[256];
    int t = threadIdx.x;
    int i = blockIdx.x * 256 + t;
    int v = (i < n) ? cnt[i] : 0;
    ls[t] = v;
    __syncthreads();
    for (int d = 1; d < 256; d <<= 1) {
        int u = (t >= d) ? ls[t - d] : 0;
        __syncthreads();
        ls[t] += u;
        __syncthreads();
    }
    int excl = ls[t] - v + bsum[blockIdx.x];
    if (i < n) rowptr[i] = excl;
    if (i == n - 1) rowptr[n] = excl + v;
}

// fill: slot via atomicSub on cnt (destroys cnt; bucket order irrelevant for a sum)
__global__ void k_fill(const int* __restrict__ src, const int* __restrict__ dst,
                       const int* __restrict__ rowptr, int* __restrict__ cnt,
                       int* __restrict__ perm, int e) {
    int i = blockIdx.x * 256 + threadIdx.x;
    if (i >= e) return;
    int d = dst[i];
    int slot = rowptr[d] + atomicSub(&cnt[d], 1) - 1;
    perm[slot] = src[i];
}

// ---------------- GEMM: [n,64] @ [64,64], epilogue * dinv[row] ----------------
__global__ __launch_bounds__(256) void k_gemm64(const float* __restrict__ in,
                                                const float* __restrict__ W,
                                                const float* __restrict__ dinv,
                                                float* __restrict__ out, int n) {
    __shared__ float Ws[64 * 64];
    __shared__ float Xs[16 * 64];
    int t = threadIdx.x;
    const float4* W4 = (const float4*)W;
    float4* Ws4 = (float4*)Ws;
#pragma unroll
    for (int i = 0; i < 4; ++i) Ws4[t + 256 * i] = W4[t + 256 * i];
    int row0 = blockIdx.x * 16;
    {
        int r = t >> 4, c4 = t & 15;
        int row = row0 + r;
        float4 v = make_float4(0.f, 0.f, 0.f, 0.f);
        if (row < n) v = ((const float4*)(in + (size_t)row * 64))[c4];
        ((float4*)Xs)[t] = v;
    }
    __syncthreads();
    int c = t & 63, g = t >> 6;
    float a0 = 0.f, a1 = 0.f, a2 = 0.f, a3 = 0.f;
#pragma unroll
    for (int k = 0; k < 64; ++k) {
        float w = Ws[k * 64 + c];
        a0 = fmaf(Xs[g * 64 + k], w, a0);
        a1 = fmaf(Xs[(g + 4) * 64 + k], w, a1);
        a2 = fmaf(Xs[(g + 8) * 64 + k], w, a2);
        a3 = fmaf(Xs[(g + 12) * 64 + k], w, a3);
    }
    int r;
    r = row0 + g;      if (r < n) out[(size_t)r * 64 + c] = a0 * dinv[r];
    r = row0 + g + 4;  if (r < n) out[(size_t)r * 64 + c] = a1 * dinv[r];
    r = row0 + g + 8;  if (r < n) out[(size_t)r * 64 + c] = a2 * dinv[r];
    r = row0 + g + 12; if (r < n) out[(size_t)r * 64 + c] = a3 * dinv[r];
}

// ---------------- GEMM: [n,64] @ [64,4], epilogue * dinv[row] ----------------
__global__ void k_gemm4(const float* __restrict__ in, const float* __restrict__ W,
                        const float* __restrict__ dinv, float* __restrict__ out, int n) {
    __shared__ float Ws[64 * 4];
    int t = threadIdx.x;
    Ws[t] = W[t];
    __syncthreads();
    int row = blockIdx.x * 256 + t;
    if (row >= n) return;
    float a0 = 0.f, a1 = 0.f, a2 = 0.f, a3 = 0.f;
    const float4* xin = (const float4*)(in + (size_t)row * 64);
#pragma unroll
    for (int k4 = 0; k4 < 16; ++k4) {
        float4 x = xin[k4];
        int k = k4 * 4;
        a0 = fmaf(x.x, Ws[k * 4 + 0], a0); a1 = fmaf(x.x, Ws[k * 4 + 1], a1);
        a2 = fmaf(x.x, Ws[k * 4 + 2], a2); a3 = fmaf(x.x, Ws[k * 4 + 3], a3);
        a0 = fmaf(x.y, Ws[k * 4 + 4], a0); a1 = fmaf(x.y, Ws[k * 4 + 5], a1);
        a2 = fmaf(x.y, Ws[k * 4 + 6], a2); a3 = fmaf(x.y, Ws[k * 4 + 7], a3);
        a0 = fmaf(x.z, Ws[k * 4 + 8], a0); a1 = fmaf(x.z, Ws[k * 4 + 9], a1);
        a2 = fmaf(x.z, Ws[k * 4 + 10], a2); a3 = fmaf(x.z, Ws[k * 4 + 11], a3);
        a0 = fmaf(x.w, Ws[k * 4 + 12], a0); a1 = fmaf(x.w, Ws[k * 4 + 13], a1);
        a2 = fmaf(x.w, Ws[k * 4 + 14], a2); a3 = fmaf(x.w, Ws[k * 4 + 15], a3);
    }
    float dv = dinv[row];
    *reinterpret_cast<float4*>(out + (size_t)row * 4) =
        make_float4(a0 * dv, a1 * dv, a2 * dv, a3 * dv);
}

// ---------------- gather 64ch: wave per node, lane = channel, unroll 8 ----------------
__global__ __launch_bounds__(256) void k_gather64(
        const float* __restrict__ h, const float* __restrict__ dinv,
        const int* __restrict__ rowptr, const int* __restrict__ perm,
        const float* __restrict__ b, float* __restrict__ out, int n, int act) {
    int t = threadIdx.x;
    int v = blockIdx.x * 4 + (t >> 6);
    if (v >= n) return;
    v = __builtin_amdgcn_readfirstlane(v);  // force SGPR: perm/rowptr become scalar loads
    int lane = t & 63;
    const float* hl = h + lane;
    float acc = hl[(size_t)v * 64];
    int e = rowptr[v], end = rowptr[v + 1];
#define LOADK(j) float x##j = hl[(size_t)perm[e + j] * 64]
    for (; e + 8 <= end; e += 8) {
        LOADK(0); LOADK(1); LOADK(2); LOADK(3);
        LOADK(4); LOADK(5); LOADK(6); LOADK(7);
        acc += ((x0 + x1) + (x2 + x3)) + ((x4 + x5) + (x6 + x7));
    }
    if (e + 4 <= end) {
        LOADK(0); LOADK(1); LOADK(2); LOADK(3);
        acc += (x0 + x1) + (x2 + x3);
        e += 4;
    }
    if (e + 2 <= end) {
        LOADK(0); LOADK(1);
        acc += x0 + x1;
        e += 2;
    }
    if (e < end) acc += hl[(size_t)perm[e] * 64];
#undef LOADK
    acc = acc * dinv[v] + b[lane];
    if (act) acc = acc > 0.0f ? acc : acc * NEG_SLOPE;
    out[(size_t)v * 64 + lane] = acc;
}

// ---------------- gather 4ch: 4 lanes per node, unroll 4 ----------------
__global__ __launch_bounds__(256) void k_gather4(
        const float* __restrict__ h, const float* __restrict__ dinv,
        const int* __restrict__ rowptr, const int* __restrict__ perm,
        const float* __restrict__ b, float* __restrict__ out, int n) {
    int gid = blockIdx.x * 256 + threadIdx.x;
    int c = gid & 3;
    int v = gid >> 2;
    if (v >= n) return;
    const float* hc = h + c;
    float acc = hc[(size_t)v * 4];
    int e = rowptr[v], end = rowptr[v + 1];
    for (; e + 4 <= end; e += 4) {
        float x0 = hc[(size_t)perm[e] * 4];
        float x1 = hc[(size_t)perm[e + 1] * 4];
        float x2 = hc[(size_t)perm[e + 2] * 4];
        float x3 = hc[(size_t)perm[e + 3] * 4];
        acc += (x0 + x1) + (x2 + x3);
    }
    for (; e < end; ++e) acc += hc[(size_t)perm[e] * 4];
    out[(size_t)v * 4 + c] = acc * dinv[v] + b[c];
}

extern "C" void kernel_launch(void* const* d_in, const int* in_sizes, int n_in,
                              void* d_out, int out_size, void* d_ws, size_t ws_size,
                              hipStream_t stream) {
    const float* x  = (const float*)d_in[0];
    const int* ei   = (const int*)d_in[1];
    const float* W0 = (const float*)d_in[2];
    const float* b0 = (const float*)d_in[3];
    const float* W1 = (const float*)d_in[4];
    const float* b1 = (const float*)d_in[5];
    const float* W2 = (const float*)d_in[6];
    const float* b2 = (const float*)d_in[7];
    float* out = (float*)d_out;

    const int N = in_sizes[0] / 64;
    const int E = in_sizes[1] / 2;
    const int* src = ei;
    const int* dst = ei + E;

    // workspace layout
    const size_t PAD_N = 50176;
    float* base = (float*)d_ws;
    int*   cnt    = (int*)base;                       // PAD_N
    float* dinv   = base + PAD_N;                     // PAD_N
    int*   rowptr = (int*)(base + 2 * PAD_N);         // N+1
    int*   bsum   = (int*)(base + 3 * PAD_N);         // nb (<=256)
    int*   perm   = (int*)(base + 3 * PAD_N + 512);   // E
    float* bufA   = base + 3 * PAD_N + 512 + (size_t)E;
    float* bufB   = bufA + (size_t)N * 64;

    const int nb_N = (N + 255) / 256;   // 196 for N=50000
    const int nb_E = (E + 255) / 256;

    // ---- CSR build + normalization ----
    hipMemsetAsync(cnt, 0, PAD_N * sizeof(int), stream);
    k_count<<<nb_E, 256, 0, stream>>>(dst, cnt, E);
    k_scan1<<<nb_N, 256, 0, stream>>>(cnt, bsum, dinv, N);
    k_scan2<<<1, 256, 0, stream>>>(bsum, nb_N);
    k_scan3<<<nb_N, 256, 0, stream>>>(cnt, bsum, rowptr, N);
    k_fill<<<nb_E, 256, 0, stream>>>(src, dst, rowptr, cnt, perm, E);

    // ---- layer 0 ----
    k_gemm64<<<(N + 15) / 16, 256, 0, stream>>>(x, W0, dinv, bufA, N);
    k_gather64<<<(N + 3) / 4, 256, 0, stream>>>(bufA, dinv, rowptr, perm, b0, bufB, N, 1);

    // ---- layer 1 ----
    k_gemm64<<<(N + 15) / 16, 256, 0, stream>>>(bufB, W1, dinv, bufA, N);
    k_gather64<<<(N + 3) / 4, 256, 0, stream>>>(bufA, dinv, rowptr, perm, b1, bufB, N, 1);

    // ---- layer 2 (d_out = 4) ----
    k_gemm4<<<nb_N, 256, 0, stream>>>(bufB, W2, dinv, bufA, N);
    k_gather4<<<(N * 4 + 255) / 256, 256, 0, stream>>>(bufA, dinv, rowptr, perm, b2, out, N);
}

// Round 5
// 207.619 us; speedup vs baseline: 3.1526x; 1.1114x over previous
//
#include <hip/hip_runtime.h>
#include <math.h>

#define NEG_SLOPE 0.2f

// ---------------- zero the packed count array ----------------
__global__ void k_zero(unsigned int* __restrict__ p, int n) {
    int i = blockIdx.x * 256 + threadIdx.x;
    if (i < n) p[i] = 0u;
}

// ---------------- rank pass: ONE atomic per edge on packed 16-bit counts ----
// cnt32[d>>1] holds counts for nodes 2k (low 16) and 2k+1 (high 16).
// atomicAdd's return value gives this edge's rank within its dst bucket.
__global__ void k_rank(const int* __restrict__ dst, unsigned int* __restrict__ cnt32,
                       unsigned short* __restrict__ rank, int e) {
    int i = blockIdx.x * 256 + threadIdx.x;
    if (i >= e) return;
    int d = dst[i];
    int sh = (d & 1) * 16;
    unsigned int old = atomicAdd(&cnt32[d >> 1], 1u << sh);
    rank[i] = (unsigned short)((old >> sh) & 0xffffu);
}

// phase 1: per-block(256 nodes) sums -> bsum; also dinv = rsqrt(cnt+1)
__global__ __launch_bounds__(256) void k_scan1(const unsigned int* __restrict__ cnt32,
                                               int* __restrict__ bsum,
                                               float* __restrict__ dinv, int n) {
    int t = threadIdx.x;
    int i = blockIdx.x * 256 + t;
    int v = 0;
    if (i < n) {
        v = (int)((cnt32[i >> 1] >> ((i & 1) * 16)) & 0xffffu);
        dinv[i] = rsqrtf((float)(v + 1));  // +1 self-loop
    }
    int s = v;
    for (int d = 1; d < 64; d <<= 1) s += __shfl_down(s, d);
    __shared__ int ws[4];
    if ((t & 63) == 0) ws[t >> 6] = s;
    __syncthreads();
    if (t == 0) bsum[blockIdx.x] = ws[0] + ws[1] + ws[2] + ws[3];
}

// phase 2+3 fused: each block reduces its bsum-prefix (nb<=256) then local scan -> rowptr
__global__ __launch_bounds__(256) void k_scan3(const unsigned int* __restrict__ cnt32,
                                               const int* __restrict__ bsum,
                                               int* __restrict__ rowptr, int n, int nb) {
    __shared__ int ls[256];
    __shared__ int wo[4];
    int t = threadIdx.x;
    int bid = blockIdx.x;
    // block offset = sum of bsum[0..bid)
    int bv = (t < bid && t < nb) ? bsum[t] : 0;
    for (int d = 1; d < 64; d <<= 1) bv += __shfl_down(bv, d);
    if ((t & 63) == 0) wo[t >> 6] = bv;
    __syncthreads();
    int boff = wo[0] + wo[1] + wo[2] + wo[3];
    // local exclusive scan of this block's 256 counts
    int i = bid * 256 + t;
    int v = 0;
    if (i < n) v = (int)((cnt32[i >> 1] >> ((i & 1) * 16)) & 0xffffu);
    ls[t] = v;
    __syncthreads();
    for (int d = 1; d < 256; d <<= 1) {
        int u = (t >= d) ? ls[t - d] : 0;
        __syncthreads();
        ls[t] += u;
        __syncthreads();
    }
    int excl = ls[t] - v + boff;
    if (i < n) rowptr[i] = excl;
    if (i == n - 1) rowptr[n] = excl + v;
}

// place pass: NO atomics — slot is rowptr[d] + precomputed rank
__global__ void k_place(const int* __restrict__ src, const int* __restrict__ dst,
                        const int* __restrict__ rowptr, const unsigned short* __restrict__ rank,
                        int* __restrict__ perm, int e) {
    int i = blockIdx.x * 256 + threadIdx.x;
    if (i >= e) return;
    int d = dst[i];
    perm[rowptr[d] + (int)rank[i]] = src[i];
}

// ---------------- GEMM: [n,64] @ [64,64], epilogue * dinv[row] ----------------
__global__ __launch_bounds__(256) void k_gemm64(const float* __restrict__ in,
                                                const float* __restrict__ W,
                                                const float* __restrict__ dinv,
                                                float* __restrict__ out, int n) {
    __shared__ float Ws[64 * 64];
    __shared__ float Xs[16 * 64];
    int t = threadIdx.x;
    const float4* W4 = (const float4*)W;
    float4* Ws4 = (float4*)Ws;
#pragma unroll
    for (int i = 0; i < 4; ++i) Ws4[t + 256 * i] = W4[t + 256 * i];
    int row0 = blockIdx.x * 16;
    {
        int r = t >> 4, c4 = t & 15;
        int row = row0 + r;
        float4 v = make_float4(0.f, 0.f, 0.f, 0.f);
        if (row < n) v = ((const float4*)(in + (size_t)row * 64))[c4];
        ((float4*)Xs)[t] = v;
    }
    __syncthreads();
    int c = t & 63, g = t >> 6;
    float a0 = 0.f, a1 = 0.f, a2 = 0.f, a3 = 0.f;
#pragma unroll
    for (int k = 0; k < 64; ++k) {
        float w = Ws[k * 64 + c];
        a0 = fmaf(Xs[g * 64 + k], w, a0);
        a1 = fmaf(Xs[(g + 4) * 64 + k], w, a1);
        a2 = fmaf(Xs[(g + 8) * 64 + k], w, a2);
        a3 = fmaf(Xs[(g + 12) * 64 + k], w, a3);
    }
    int r;
    r = row0 + g;      if (r < n) out[(size_t)r * 64 + c] = a0 * dinv[r];
    r = row0 + g + 4;  if (r < n) out[(size_t)r * 64 + c] = a1 * dinv[r];
    r = row0 + g + 8;  if (r < n) out[(size_t)r * 64 + c] = a2 * dinv[r];
    r = row0 + g + 12; if (r < n) out[(size_t)r * 64 + c] = a3 * dinv[r];
}

// ---------------- GEMM: [n,64] @ [64,4], epilogue * dinv[row] ----------------
__global__ void k_gemm4(const float* __restrict__ in, const float* __restrict__ W,
                        const float* __restrict__ dinv, float* __restrict__ out, int n) {
    __shared__ float Ws[64 * 4];
    int t = threadIdx.x;
    Ws[t] = W[t];
    __syncthreads();
    int row = blockIdx.x * 256 + t;
    if (row >= n) return;
    float a0 = 0.f, a1 = 0.f, a2 = 0.f, a3 = 0.f;
    const float4* xin = (const float4*)(in + (size_t)row * 64);
#pragma unroll
    for (int k4 = 0; k4 < 16; ++k4) {
        float4 x = xin[k4];
        int k = k4 * 4;
        a0 = fmaf(x.x, Ws[k * 4 + 0], a0); a1 = fmaf(x.x, Ws[k * 4 + 1], a1);
        a2 = fmaf(x.x, Ws[k * 4 + 2], a2); a3 = fmaf(x.x, Ws[k * 4 + 3], a3);
        a0 = fmaf(x.y, Ws[k * 4 + 4], a0); a1 = fmaf(x.y, Ws[k * 4 + 5], a1);
        a2 = fmaf(x.y, Ws[k * 4 + 6], a2); a3 = fmaf(x.y, Ws[k * 4 + 7], a3);
        a0 = fmaf(x.z, Ws[k * 4 + 8], a0); a1 = fmaf(x.z, Ws[k * 4 + 9], a1);
        a2 = fmaf(x.z, Ws[k * 4 + 10], a2); a3 = fmaf(x.z, Ws[k * 4 + 11], a3);
        a0 = fmaf(x.w, Ws[k * 4 + 12], a0); a1 = fmaf(x.w, Ws[k * 4 + 13], a1);
        a2 = fmaf(x.w, Ws[k * 4 + 14], a2); a3 = fmaf(x.w, Ws[k * 4 + 15], a3);
    }
    float dv = dinv[row];
    *reinterpret_cast<float4*>(out + (size_t)row * 4) =
        make_float4(a0 * dv, a1 * dv, a2 * dv, a3 * dv);
}

// ---------------- gather 64ch: wave per node, lane = channel, unroll 8 ----------------
__global__ __launch_bounds__(256) void k_gather64(
        const float* __restrict__ h, const float* __restrict__ dinv,
        const int* __restrict__ rowptr, const int* __restrict__ perm,
        const float* __restrict__ b, float* __restrict__ out, int n, int act) {
    int t = threadIdx.x;
    int v = blockIdx.x * 4 + (t >> 6);
    if (v >= n) return;
    v = __builtin_amdgcn_readfirstlane(v);  // force SGPR: perm/rowptr become scalar loads
    int lane = t & 63;
    const float* hl = h + lane;
    float acc = hl[(size_t)v * 64];
    int e = rowptr[v], end = rowptr[v + 1];
#define LOADK(j) float x##j = hl[(size_t)perm[e + j] * 64]
    for (; e + 8 <= end; e += 8) {
        LOADK(0); LOADK(1); LOADK(2); LOADK(3);
        LOADK(4); LOADK(5); LOADK(6); LOADK(7);
        acc += ((x0 + x1) + (x2 + x3)) + ((x4 + x5) + (x6 + x7));
    }
    if (e + 4 <= end) {
        LOADK(0); LOADK(1); LOADK(2); LOADK(3);
        acc += (x0 + x1) + (x2 + x3);
        e += 4;
    }
    if (e + 2 <= end) {
        LOADK(0); LOADK(1);
        acc += x0 + x1;
        e += 2;
    }
    if (e < end) acc += hl[(size_t)perm[e] * 64];
#undef LOADK
    acc = acc * dinv[v] + b[lane];
    if (act) acc = acc > 0.0f ? acc : acc * NEG_SLOPE;
    out[(size_t)v * 64 + lane] = acc;
}

// ---------------- gather 4ch: 4 lanes per node, unroll 4 ----------------
__global__ __launch_bounds__(256) void k_gather4(
        const float* __restrict__ h, const float* __restrict__ dinv,
        const int* __restrict__ rowptr, const int* __restrict__ perm,
        const float* __restrict__ b, float* __restrict__ out, int n) {
    int gid = blockIdx.x * 256 + threadIdx.x;
    int c = gid & 3;
    int v = gid >> 2;
    if (v >= n) return;
    const float* hc = h + c;
    float acc = hc[(size_t)v * 4];
    int e = rowptr[v], end = rowptr[v + 1];
    for (; e + 4 <= end; e += 4) {
        float x0 = hc[(size_t)perm[e] * 4];
        float x1 = hc[(size_t)perm[e + 1] * 4];
        float x2 = hc[(size_t)perm[e + 2] * 4];
        float x3 = hc[(size_t)perm[e + 3] * 4];
        acc += (x0 + x1) + (x2 + x3);
    }
    for (; e < end; ++e) acc += hc[(size_t)perm[e] * 4];
    out[(size_t)v * 4 + c] = acc * dinv[v] + b[c];
}

extern "C" void kernel_launch(void* const* d_in, const int* in_sizes, int n_in,
                              void* d_out, int out_size, void* d_ws, size_t ws_size,
                              hipStream_t stream) {
    const float* x  = (const float*)d_in[0];
    const int* ei   = (const int*)d_in[1];
    const float* W0 = (const float*)d_in[2];
    const float* b0 = (const float*)d_in[3];
    const float* W1 = (const float*)d_in[4];
    const float* b1 = (const float*)d_in[5];
    const float* W2 = (const float*)d_in[6];
    const float* b2 = (const float*)d_in[7];
    float* out = (float*)d_out;

    const int N = in_sizes[0] / 64;
    const int E = in_sizes[1] / 2;
    const int* src = ei;
    const int* dst = ei + E;

    // workspace layout (byte offsets, all 16B-aligned)
    char* base = (char*)d_ws;
    const int NC32 = 25088;  // 50176 nodes / 2 packed per u32
    unsigned int*   cnt32  = (unsigned int*)(base);                 // 100352 B
    float*          dinv   = (float*)(base + 100352);               // 200704 B
    int*            rowptr = (int*)(base + 301056);                 // 200704 B (N+1 used)
    int*            bsum   = (int*)(base + 501760);                 // 2048 B
    unsigned short* rank   = (unsigned short*)(base + 503808);      // 1.6 MB
    int*            perm   = (int*)(base + 2103808);                // 3.2 MB
    float*          bufA   = (float*)(base + 5303808);              // 12.8 MB
    float*          bufB   = (float*)(base + 18103808);             // 12.8 MB

    const int nb_N = (N + 255) / 256;   // 196 for N=50000
    const int nb_E = (E + 255) / 256;

    // ---- CSR build + normalization ----
    k_zero<<<(NC32 + 255) / 256, 256, 0, stream>>>(cnt32, NC32);
    k_rank<<<nb_E, 256, 0, stream>>>(dst, cnt32, rank, E);
    k_scan1<<<nb_N, 256, 0, stream>>>(cnt32, bsum, dinv, N);
    k_scan3<<<nb_N, 256, 0, stream>>>(cnt32, bsum, rowptr, N, nb_N);
    k_place<<<nb_E, 256, 0, stream>>>(src, dst, rowptr, rank, perm, E);

    // ---- layer 0 ----
    k_gemm64<<<(N + 15) / 16, 256, 0, stream>>>(x, W0, dinv, bufA, N);
    k_gather64<<<(N + 3) / 4, 256, 0, stream>>>(bufA, dinv, rowptr, perm, b0, bufB, N, 1);

    // ---- layer 1 ----
    k_gemm64<<<(N + 15) / 16, 256, 0, stream>>>(bufB, W1, dinv, bufA, N);
    k_gather64<<<(N + 3) / 4, 256, 0, stream>>>(bufA, dinv, rowptr, perm, b1, bufB, N, 1);

    // ---- layer 2 (d_out = 4) ----
    k_gemm4<<<nb_N, 256, 0, stream>>>(bufB, W2, dinv, bufA, N);
    k_gather4<<<(N * 4 + 255) / 256, 256, 0, stream>>>(bufA, dinv, rowptr, perm, b2, out, N);
}

// Round 6
// 187.499 us; speedup vs baseline: 3.4908x; 1.1073x over previous
//
#include <hip/hip_runtime.h>
#include <math.h>

#define NEG_SLOPE 0.2f
#define NPAD 50176            // node capacity (multiple of 512)
#define NW   (NPAD / 2)       // packed u32 cells (2 x u16 counts)
#define NCHUNK 256            // edge chunks == k_hist blocks

// ---- phase 1: per-chunk histogram via LDS atomics; emits within-chunk rank ----
__global__ __launch_bounds__(1024) void k_hist(const int* __restrict__ dst,
                                               unsigned int* __restrict__ histw,
                                               unsigned short* __restrict__ rank,
                                               int e, int es) {
    extern __shared__ unsigned int lcnt[];  // NW u32 = 100352 B
    int t = threadIdx.x;
    for (int w = t; w < NW; w += 1024) lcnt[w] = 0u;
    __syncthreads();
    int beg = blockIdx.x * es;
    int end = min(beg + es, e);
    for (int i = beg + t; i < end; i += 1024) {
        int d = dst[i];
        int sh = (d & 1) << 4;
        unsigned int old = atomicAdd(&lcnt[d >> 1], 1u << sh);
        rank[i] = (unsigned short)((old >> sh) & 0xffffu);
    }
    __syncthreads();
    unsigned int* out = histw + (size_t)blockIdx.x * NW;
    for (int w = t; w < NW; w += 1024) out[w] = lcnt[w];
}

// ---- phase 2: per-node exclusive scan over chunks (in place), deg/dinv/bsum ----
__global__ __launch_bounds__(256) void k_chscan(unsigned short* __restrict__ hist16,
                                                float* __restrict__ dinv,
                                                unsigned short* __restrict__ deg16,
                                                int* __restrict__ bsum, int n) {
    int t = threadIdx.x;
    int i = blockIdx.x * 256 + t;          // grid covers NPAD exactly
    unsigned short* p = hist16 + i;
    unsigned int run = 0;
    for (int c = 0; c < NCHUNK; c += 8) {
        size_t b = (size_t)c * NPAD;
        unsigned short v0 = p[b];
        unsigned short v1 = p[b + (size_t)1 * NPAD];
        unsigned short v2 = p[b + (size_t)2 * NPAD];
        unsigned short v3 = p[b + (size_t)3 * NPAD];
        unsigned short v4 = p[b + (size_t)4 * NPAD];
        unsigned short v5 = p[b + (size_t)5 * NPAD];
        unsigned short v6 = p[b + (size_t)6 * NPAD];
        unsigned short v7 = p[b + (size_t)7 * NPAD];
        unsigned int e0 = run;
        unsigned int e1 = e0 + v0;
        unsigned int e2 = e1 + v1;
        unsigned int e3 = e2 + v2;
        unsigned int e4 = e3 + v3;
        unsigned int e5 = e4 + v4;
        unsigned int e6 = e5 + v5;
        unsigned int e7 = e6 + v6;
        run = e7 + v7;
        p[b] = (unsigned short)e0;
        p[b + (size_t)1 * NPAD] = (unsigned short)e1;
        p[b + (size_t)2 * NPAD] = (unsigned short)e2;
        p[b + (size_t)3 * NPAD] = (unsigned short)e3;
        p[b + (size_t)4 * NPAD] = (unsigned short)e4;
        p[b + (size_t)5 * NPAD] = (unsigned short)e5;
        p[b + (size_t)6 * NPAD] = (unsigned short)e6;
        p[b + (size_t)7 * NPAD] = (unsigned short)e7;
    }
    int deg = (int)run;
    if (i < n) dinv[i] = rsqrtf((float)(deg + 1));  // +1 self-loop
    deg16[i] = (unsigned short)deg;                 // zero beyond n
    int s = deg;
    for (int d = 1; d < 64; d <<= 1) s += __shfl_down(s, d);
    __shared__ int ws[4];
    if ((t & 63) == 0) ws[t >> 6] = s;
    __syncthreads();
    if (t == 0) bsum[blockIdx.x] = ws[0] + ws[1] + ws[2] + ws[3];
}

// ---- phase 3: rowptr = global exclusive scan (block prefix of bsum + local scan) ----
__global__ __launch_bounds__(256) void k_scan3(const unsigned short* __restrict__ deg16,
                                               const int* __restrict__ bsum,
                                               int* __restrict__ rowptr, int n, int nb) {
    __shared__ int ls[256];
    __shared__ int wo[4];
    int t = threadIdx.x;
    int bid = blockIdx.x;
    int bv = (t < bid && t < nb) ? bsum[t] : 0;
    for (int d = 1; d < 64; d <<= 1) bv += __shfl_down(bv, d);
    if ((t & 63) == 0) wo[t >> 6] = bv;
    __syncthreads();
    int boff = wo[0] + wo[1] + wo[2] + wo[3];
    int i = bid * 256 + t;
    int v = (i < n) ? (int)deg16[i] : 0;
    ls[t] = v;
    __syncthreads();
    for (int d = 1; d < 256; d <<= 1) {
        int u = (t >= d) ? ls[t - d] : 0;
        __syncthreads();
        ls[t] += u;
        __syncthreads();
    }
    int excl = ls[t] - v + boff;
    if (i < n) rowptr[i] = excl;
    if (i == n - 1) rowptr[n] = excl + v;
}

// ---- phase 4: place (no atomics) ----
__global__ void k_place(const int* __restrict__ src, const int* __restrict__ dst,
                        const int* __restrict__ rowptr, const unsigned short* __restrict__ rank,
                        const unsigned short* __restrict__ choff,
                        int* __restrict__ perm, int e, int es) {
    int i = blockIdx.x * 256 + threadIdx.x;
    if (i >= e) return;
    int d = dst[i];
    unsigned int c = (unsigned int)i / (unsigned int)es;
    int slot = rowptr[d] + (int)choff[(size_t)c * NPAD + d] + (int)rank[i];
    perm[slot] = src[i];
}

// ---------------- GEMM: [n,64] @ [64,64], epilogue * dinv[row] ----------------
__global__ __launch_bounds__(256) void k_gemm64(const float* __restrict__ in,
                                                const float* __restrict__ W,
                                                const float* __restrict__ dinv,
                                                float* __restrict__ out, int n) {
    __shared__ float Ws[64 * 64];
    __shared__ float Xs[16 * 64];
    int t = threadIdx.x;
    const float4* W4 = (const float4*)W;
    float4* Ws4 = (float4*)Ws;
#pragma unroll
    for (int i = 0; i < 4; ++i) Ws4[t + 256 * i] = W4[t + 256 * i];
    int row0 = blockIdx.x * 16;
    {
        int r = t >> 4, c4 = t & 15;
        int row = row0 + r;
        float4 v = make_float4(0.f, 0.f, 0.f, 0.f);
        if (row < n) v = ((const float4*)(in + (size_t)row * 64))[c4];
        ((float4*)Xs)[t] = v;
    }
    __syncthreads();
    int c = t & 63, g = t >> 6;
    float a0 = 0.f, a1 = 0.f, a2 = 0.f, a3 = 0.f;
#pragma unroll
    for (int k = 0; k < 64; ++k) {
        float w = Ws[k * 64 + c];
        a0 = fmaf(Xs[g * 64 + k], w, a0);
        a1 = fmaf(Xs[(g + 4) * 64 + k], w, a1);
        a2 = fmaf(Xs[(g + 8) * 64 + k], w, a2);
        a3 = fmaf(Xs[(g + 12) * 64 + k], w, a3);
    }
    int r;
    r = row0 + g;      if (r < n) out[(size_t)r * 64 + c] = a0 * dinv[r];
    r = row0 + g + 4;  if (r < n) out[(size_t)r * 64 + c] = a1 * dinv[r];
    r = row0 + g + 8;  if (r < n) out[(size_t)r * 64 + c] = a2 * dinv[r];
    r = row0 + g + 12; if (r < n) out[(size_t)r * 64 + c] = a3 * dinv[r];
}

// ---------------- GEMM: [n,64] @ [64,4], epilogue * dinv[row] ----------------
__global__ void k_gemm4(const float* __restrict__ in, const float* __restrict__ W,
                        const float* __restrict__ dinv, float* __restrict__ out, int n) {
    __shared__ float Ws[64 * 4];
    int t = threadIdx.x;
    Ws[t] = W[t];
    __syncthreads();
    int row = blockIdx.x * 256 + t;
    if (row >= n) return;
    float a0 = 0.f, a1 = 0.f, a2 = 0.f, a3 = 0.f;
    const float4* xin = (const float4*)(in + (size_t)row * 64);
#pragma unroll
    for (int k4 = 0; k4 < 16; ++k4) {
        float4 x = xin[k4];
        int k = k4 * 4;
        a0 = fmaf(x.x, Ws[k * 4 + 0], a0); a1 = fmaf(x.x, Ws[k * 4 + 1], a1);
        a2 = fmaf(x.x, Ws[k * 4 + 2], a2); a3 = fmaf(x.x, Ws[k * 4 + 3], a3);
        a0 = fmaf(x.y, Ws[k * 4 + 4], a0); a1 = fmaf(x.y, Ws[k * 4 + 5], a1);
        a2 = fmaf(x.y, Ws[k * 4 + 6], a2); a3 = fmaf(x.y, Ws[k * 4 + 7], a3);
        a0 = fmaf(x.z, Ws[k * 4 + 8], a0); a1 = fmaf(x.z, Ws[k * 4 + 9], a1);
        a2 = fmaf(x.z, Ws[k * 4 + 10], a2); a3 = fmaf(x.z, Ws[k * 4 + 11], a3);
        a0 = fmaf(x.w, Ws[k * 4 + 12], a0); a1 = fmaf(x.w, Ws[k * 4 + 13], a1);
        a2 = fmaf(x.w, Ws[k * 4 + 14], a2); a3 = fmaf(x.w, Ws[k * 4 + 15], a3);
    }
    float dv = dinv[row];
    *reinterpret_cast<float4*>(out + (size_t)row * 4) =
        make_float4(a0 * dv, a1 * dv, a2 * dv, a3 * dv);
}

// ---------------- gather 64ch: wave per node, lane = channel, unroll 8 ----------------
__global__ __launch_bounds__(256) void k_gather64(
        const float* __restrict__ h, const float* __restrict__ dinv,
        const int* __restrict__ rowptr, const int* __restrict__ perm,
        const float* __restrict__ b, float* __restrict__ out, int n, int act) {
    int t = threadIdx.x;
    int v = blockIdx.x * 4 + (t >> 6);
    if (v >= n) return;
    v = __builtin_amdgcn_readfirstlane(v);  // force SGPR: perm/rowptr become scalar loads
    int lane = t & 63;
    const float* hl = h + lane;
    float acc = hl[(size_t)v * 64];
    int e = rowptr[v], end = rowptr[v + 1];
#define LOADK(j) float x##j = hl[(size_t)perm[e + j] * 64]
    for (; e + 8 <= end; e += 8) {
        LOADK(0); LOADK(1); LOADK(2); LOADK(3);
        LOADK(4); LOADK(5); LOADK(6); LOADK(7);
        acc += ((x0 + x1) + (x2 + x3)) + ((x4 + x5) + (x6 + x7));
    }
    if (e + 4 <= end) {
        LOADK(0); LOADK(1); LOADK(2); LOADK(3);
        acc += (x0 + x1) + (x2 + x3);
        e += 4;
    }
    if (e + 2 <= end) {
        LOADK(0); LOADK(1);
        acc += x0 + x1;
        e += 2;
    }
    if (e < end) acc += hl[(size_t)perm[e] * 64];
#undef LOADK
    acc = acc * dinv[v] + b[lane];
    if (act) acc = acc > 0.0f ? acc : acc * NEG_SLOPE;
    out[(size_t)v * 64 + lane] = acc;
}

// ---------------- gather 4ch: 4 lanes per node, unroll 4 ----------------
__global__ __launch_bounds__(256) void k_gather4(
        const float* __restrict__ h, const float* __restrict__ dinv,
        const int* __restrict__ rowptr, const int* __restrict__ perm,
        const float* __restrict__ b, float* __restrict__ out, int n) {
    int gid = blockIdx.x * 256 + threadIdx.x;
    int c = gid & 3;
    int v = gid >> 2;
    if (v >= n) return;
    const float* hc = h + c;
    float acc = hc[(size_t)v * 4];
    int e = rowptr[v], end = rowptr[v + 1];
    for (; e + 4 <= end; e += 4) {
        float x0 = hc[(size_t)perm[e] * 4];
        float x1 = hc[(size_t)perm[e + 1] * 4];
        float x2 = hc[(size_t)perm[e + 2] * 4];
        float x3 = hc[(size_t)perm[e + 3] * 4];
        acc += (x0 + x1) + (x2 + x3);
    }
    for (; e < end; ++e) acc += hc[(size_t)perm[e] * 4];
    out[(size_t)v * 4 + c] = acc * dinv[v] + b[c];
}

extern "C" void kernel_launch(void* const* d_in, const int* in_sizes, int n_in,
                              void* d_out, int out_size, void* d_ws, size_t ws_size,
                              hipStream_t stream) {
    const float* x  = (const float*)d_in[0];
    const int* ei   = (const int*)d_in[1];
    const float* W0 = (const float*)d_in[2];
    const float* b0 = (const float*)d_in[3];
    const float* W1 = (const float*)d_in[4];
    const float* b1 = (const float*)d_in[5];
    const float* W2 = (const float*)d_in[6];
    const float* b2 = (const float*)d_in[7];
    float* out = (float*)d_out;

    const int N = in_sizes[0] / 64;
    const int E = in_sizes[1] / 2;
    const int* src = ei;
    const int* dst = ei + E;
    const int es = (E + NCHUNK - 1) / NCHUNK;   // edges per chunk

    // workspace layout, 256B-aligned slabs
    char* base = (char*)d_ws;
    size_t off = 0;
    auto alloc = [&](size_t bytes) { size_t o = off; off = (off + bytes + 255) & ~(size_t)255; return o; };
    unsigned int*   histw  = (unsigned int*)(base + alloc((size_t)NCHUNK * NPAD * 2));  // u16[C][NPAD]
    unsigned short* rank   = (unsigned short*)(base + alloc((size_t)E * 2));
    unsigned short* deg16  = (unsigned short*)(base + alloc((size_t)NPAD * 2));
    float*          dinv   = (float*)(base + alloc((size_t)NPAD * 4));
    int*            rowptr = (int*)(base + alloc((size_t)(NPAD + 1) * 4));
    int*            bsum   = (int*)(base + alloc(1024));
    int*            perm   = (int*)(base + alloc((size_t)E * 4));
    float*          bufA   = (float*)(base + alloc((size_t)N * 64 * 4));
    float*          bufB   = (float*)(base + alloc((size_t)N * 64 * 4));

    const int nb_N = (N + 255) / 256;   // 196
    const int nb_E = (E + 255) / 256;

    // ---- CSR build + normalization (no global atomics) ----
    k_hist<<<NCHUNK, 1024, NW * sizeof(unsigned int), stream>>>(dst, histw, rank, E, es);
    k_chscan<<<NPAD / 256, 256, 0, stream>>>((unsigned short*)histw, dinv, deg16, bsum, N);
    k_scan3<<<nb_N, 256, 0, stream>>>(deg16, bsum, rowptr, N, nb_N);
    k_place<<<nb_E, 256, 0, stream>>>(src, dst, rowptr, rank, (const unsigned short*)histw, perm, E, es);

    // ---- layer 0 ----
    k_gemm64<<<(N + 15) / 16, 256, 0, stream>>>(x, W0, dinv, bufA, N);
    k_gather64<<<(N + 3) / 4, 256, 0, stream>>>(bufA, dinv, rowptr, perm, b0, bufB, N, 1);

    // ---- layer 1 ----
    k_gemm64<<<(N + 15) / 16, 256, 0, stream>>>(bufB, W1, dinv, bufA, N);
    k_gather64<<<(N + 3) / 4, 256, 0, stream>>>(bufA, dinv, rowptr, perm, b1, bufB, N, 1);

    // ---- layer 2 (d_out = 4) ----
    k_gemm4<<<nb_N, 256, 0, stream>>>(bufB, W2, dinv, bufA, N);
    k_gather4<<<(N * 4 + 255) / 256, 256, 0, stream>>>(bufA, dinv, rowptr, perm, b2, out, N);
}

// Round 7
// 183.230 us; speedup vs baseline: 3.5722x; 1.0233x over previous
//
#include <hip/hip_runtime.h>
#include <math.h>

#define NEG_SLOPE 0.2f
#define NPAD 50176            // node capacity (multiple of 512)
#define NW8  (NPAD / 4)       // packed u32 cells (4 x u8 counts)
#define NCHUNK 256            // edge chunks == k_hist blocks

// ---- phase 1: per-chunk histogram via LDS atomics (4x u8 packed); emits rank ----
__global__ __launch_bounds__(1024) void k_hist(const int* __restrict__ dst,
                                               unsigned int* __restrict__ histw,
                                               unsigned char* __restrict__ rank,
                                               int e, int es) {
    extern __shared__ unsigned int lcnt[];  // NW8 u32 = 50176 B
    int t = threadIdx.x;
    for (int w = t; w < NW8; w += 1024) lcnt[w] = 0u;
    __syncthreads();
    int beg = blockIdx.x * es;
    int end = min(beg + es, e);
    for (int i = beg + t; i < end; i += 1024) {
        int d = dst[i];
        int sh = (d & 3) << 3;
        unsigned int old = atomicAdd(&lcnt[d >> 2], 1u << sh);
        rank[i] = (unsigned char)((old >> sh) & 0xffu);
    }
    __syncthreads();
    unsigned int* out = histw + (size_t)blockIdx.x * NW8;
    for (int w = t; w < NW8; w += 1024) out[w] = lcnt[w];
}

// ---- phase 2: per-node exclusive scan over chunks (in place, u8), deg/dinv/bsum ----
__global__ __launch_bounds__(256) void k_chscan(unsigned char* __restrict__ hist8,
                                                float* __restrict__ dinv,
                                                unsigned short* __restrict__ deg16,
                                                int* __restrict__ bsum, int n) {
    int t = threadIdx.x;
    int i = blockIdx.x * 256 + t;          // grid covers NPAD exactly
    unsigned char* p = hist8 + i;
    unsigned int run = 0;
    for (int c = 0; c < NCHUNK; c += 8) {
        size_t b = (size_t)c * NPAD;
        unsigned char v0 = p[b];
        unsigned char v1 = p[b + (size_t)1 * NPAD];
        unsigned char v2 = p[b + (size_t)2 * NPAD];
        unsigned char v3 = p[b + (size_t)3 * NPAD];
        unsigned char v4 = p[b + (size_t)4 * NPAD];
        unsigned char v5 = p[b + (size_t)5 * NPAD];
        unsigned char v6 = p[b + (size_t)6 * NPAD];
        unsigned char v7 = p[b + (size_t)7 * NPAD];
        unsigned int e0 = run;
        unsigned int e1 = e0 + v0;
        unsigned int e2 = e1 + v1;
        unsigned int e3 = e2 + v2;
        unsigned int e4 = e3 + v3;
        unsigned int e5 = e4 + v4;
        unsigned int e6 = e5 + v5;
        unsigned int e7 = e6 + v6;
        run = e7 + v7;
        p[b] = (unsigned char)e0;
        p[b + (size_t)1 * NPAD] = (unsigned char)e1;
        p[b + (size_t)2 * NPAD] = (unsigned char)e2;
        p[b + (size_t)3 * NPAD] = (unsigned char)e3;
        p[b + (size_t)4 * NPAD] = (unsigned char)e4;
        p[b + (size_t)5 * NPAD] = (unsigned char)e5;
        p[b + (size_t)6 * NPAD] = (unsigned char)e6;
        p[b + (size_t)7 * NPAD] = (unsigned char)e7;
    }
    int deg = (int)run;
    if (i < n) dinv[i] = rsqrtf((float)(deg + 1));  // +1 self-loop
    deg16[i] = (unsigned short)deg;                 // zero beyond n
    int s = deg;
    for (int d = 1; d < 64; d <<= 1) s += __shfl_down(s, d);
    __shared__ int ws[4];
    if ((t & 63) == 0) ws[t >> 6] = s;
    __syncthreads();
    if (t == 0) bsum[blockIdx.x] = ws[0] + ws[1] + ws[2] + ws[3];
}

// ---- phase 3: rowptr = global exclusive scan (block prefix of bsum + local scan) ----
__global__ __launch_bounds__(256) void k_scan3(const unsigned short* __restrict__ deg16,
                                               const int* __restrict__ bsum,
                                               int* __restrict__ rowptr, int n, int nb) {
    __shared__ int ls[256];
    __shared__ int wo[4];
    int t = threadIdx.x;
    int bid = blockIdx.x;
    int bv = (t < bid && t < nb) ? bsum[t] : 0;
    for (int d = 1; d < 64; d <<= 1) bv += __shfl_down(bv, d);
    if ((t & 63) == 0) wo[t >> 6] = bv;
    __syncthreads();
    int boff = wo[0] + wo[1] + wo[2] + wo[3];
    int i = bid * 256 + t;
    int v = (i < n) ? (int)deg16[i] : 0;
    ls[t] = v;
    __syncthreads();
    for (int d = 1; d < 256; d <<= 1) {
        int u = (t >= d) ? ls[t - d] : 0;
        __syncthreads();
        ls[t] += u;
        __syncthreads();
    }
    int excl = ls[t] - v + boff;
    if (i < n) rowptr[i] = excl;
    if (i == n - 1) rowptr[n] = excl + v;
}

// ---- phase 4: place (no atomics) ----
__global__ void k_place(const int* __restrict__ src, const int* __restrict__ dst,
                        const int* __restrict__ rowptr, const unsigned char* __restrict__ rank,
                        const unsigned char* __restrict__ choff,
                        int* __restrict__ perm, int e, int es) {
    int i = blockIdx.x * 256 + threadIdx.x;
    if (i >= e) return;
    int d = dst[i];
    unsigned int c = (unsigned int)i / (unsigned int)es;
    int slot = rowptr[d] + (int)choff[(size_t)c * NPAD + d] + (int)rank[i];
    perm[slot] = src[i];
}

// ---------------- GEMM: [n,64] @ [64,64], epilogue * dinv[row] ----------------
__global__ __launch_bounds__(256) void k_gemm64(const float* __restrict__ in,
                                                const float* __restrict__ W,
                                                const float* __restrict__ dinv,
                                                float* __restrict__ out, int n) {
    __shared__ float Ws[64 * 64];
    __shared__ float Xs[16 * 64];
    int t = threadIdx.x;
    const float4* W4 = (const float4*)W;
    float4* Ws4 = (float4*)Ws;
#pragma unroll
    for (int i = 0; i < 4; ++i) Ws4[t + 256 * i] = W4[t + 256 * i];
    int row0 = blockIdx.x * 16;
    {
        int r = t >> 4, c4 = t & 15;
        int row = row0 + r;
        float4 v = make_float4(0.f, 0.f, 0.f, 0.f);
        if (row < n) v = ((const float4*)(in + (size_t)row * 64))[c4];
        ((float4*)Xs)[t] = v;
    }
    __syncthreads();
    int c = t & 63, g = t >> 6;
    float a0 = 0.f, a1 = 0.f, a2 = 0.f, a3 = 0.f;
#pragma unroll
    for (int k = 0; k < 64; ++k) {
        float w = Ws[k * 64 + c];
        a0 = fmaf(Xs[g * 64 + k], w, a0);
        a1 = fmaf(Xs[(g + 4) * 64 + k], w, a1);
        a2 = fmaf(Xs[(g + 8) * 64 + k], w, a2);
        a3 = fmaf(Xs[(g + 12) * 64 + k], w, a3);
    }
    int r;
    r = row0 + g;      if (r < n) out[(size_t)r * 64 + c] = a0 * dinv[r];
    r = row0 + g + 4;  if (r < n) out[(size_t)r * 64 + c] = a1 * dinv[r];
    r = row0 + g + 8;  if (r < n) out[(size_t)r * 64 + c] = a2 * dinv[r];
    r = row0 + g + 12; if (r < n) out[(size_t)r * 64 + c] = a3 * dinv[r];
}

// ---------------- GEMM: [n,64] @ [64,4], epilogue * dinv[row] ----------------
__global__ void k_gemm4(const float* __restrict__ in, const float* __restrict__ W,
                        const float* __restrict__ dinv, float* __restrict__ out, int n) {
    __shared__ float Ws[64 * 4];
    int t = threadIdx.x;
    Ws[t] = W[t];
    __syncthreads();
    int row = blockIdx.x * 256 + t;
    if (row >= n) return;
    float a0 = 0.f, a1 = 0.f, a2 = 0.f, a3 = 0.f;
    const float4* xin = (const float4*)(in + (size_t)row * 64);
#pragma unroll
    for (int k4 = 0; k4 < 16; ++k4) {
        float4 x = xin[k4];
        int k = k4 * 4;
        a0 = fmaf(x.x, Ws[k * 4 + 0], a0); a1 = fmaf(x.x, Ws[k * 4 + 1], a1);
        a2 = fmaf(x.x, Ws[k * 4 + 2], a2); a3 = fmaf(x.x, Ws[k * 4 + 3], a3);
        a0 = fmaf(x.y, Ws[k * 4 + 4], a0); a1 = fmaf(x.y, Ws[k * 4 + 5], a1);
        a2 = fmaf(x.y, Ws[k * 4 + 6], a2); a3 = fmaf(x.y, Ws[k * 4 + 7], a3);
        a0 = fmaf(x.z, Ws[k * 4 + 8], a0); a1 = fmaf(x.z, Ws[k * 4 + 9], a1);
        a2 = fmaf(x.z, Ws[k * 4 + 10], a2); a3 = fmaf(x.z, Ws[k * 4 + 11], a3);
        a0 = fmaf(x.w, Ws[k * 4 + 12], a0); a1 = fmaf(x.w, Ws[k * 4 + 13], a1);
        a2 = fmaf(x.w, Ws[k * 4 + 14], a2); a3 = fmaf(x.w, Ws[k * 4 + 15], a3);
    }
    float dv = dinv[row];
    *reinterpret_cast<float4*>(out + (size_t)row * 4) =
        make_float4(a0 * dv, a1 * dv, a2 * dv, a3 * dv);
}

// ---------------- gather 64ch: wave per node, lane = channel, unroll 16/8/4/2/1 ----
__global__ __launch_bounds__(256) void k_gather64(
        const float* __restrict__ h, const float* __restrict__ dinv,
        const int* __restrict__ rowptr, const int* __restrict__ perm,
        const float* __restrict__ b, float* __restrict__ out, int n, int act) {
    int t = threadIdx.x;
    int v = blockIdx.x * 4 + (t >> 6);
    if (v >= n) return;
    v = __builtin_amdgcn_readfirstlane(v);  // force SGPR: perm/rowptr become scalar loads
    int lane = t & 63;
    const float* hl = h + lane;
    float acc = hl[(size_t)v * 64];
    int e = rowptr[v], end = rowptr[v + 1];
#define LOADK(j) float x##j = hl[(size_t)perm[e + j] * 64]
    for (; e + 16 <= end; e += 16) {
        LOADK(0); LOADK(1); LOADK(2); LOADK(3);
        LOADK(4); LOADK(5); LOADK(6); LOADK(7);
        LOADK(8); LOADK(9); LOADK(10); LOADK(11);
        LOADK(12); LOADK(13); LOADK(14); LOADK(15);
        acc += (((x0 + x1) + (x2 + x3)) + ((x4 + x5) + (x6 + x7)))
             + (((x8 + x9) + (x10 + x11)) + ((x12 + x13) + (x14 + x15)));
    }
    if (e + 8 <= end) {
        LOADK(0); LOADK(1); LOADK(2); LOADK(3);
        LOADK(4); LOADK(5); LOADK(6); LOADK(7);
        acc += ((x0 + x1) + (x2 + x3)) + ((x4 + x5) + (x6 + x7));
        e += 8;
    }
    if (e + 4 <= end) {
        LOADK(0); LOADK(1); LOADK(2); LOADK(3);
        acc += (x0 + x1) + (x2 + x3);
        e += 4;
    }
    if (e + 2 <= end) {
        LOADK(0); LOADK(1);
        acc += x0 + x1;
        e += 2;
    }
    if (e < end) acc += hl[(size_t)perm[e] * 64];
#undef LOADK
    acc = acc * dinv[v] + b[lane];
    if (act) acc = acc > 0.0f ? acc : acc * NEG_SLOPE;
    out[(size_t)v * 64 + lane] = acc;
}

// ---------------- gather 4ch: 4 lanes per node, unroll 4 ----------------
__global__ __launch_bounds__(256) void k_gather4(
        const float* __restrict__ h, const float* __restrict__ dinv,
        const int* __restrict__ rowptr, const int* __restrict__ perm,
        const float* __restrict__ b, float* __restrict__ out, int n) {
    int gid = blockIdx.x * 256 + threadIdx.x;
    int c = gid & 3;
    int v = gid >> 2;
    if (v >= n) return;
    const float* hc = h + c;
    float acc = hc[(size_t)v * 4];
    int e = rowptr[v], end = rowptr[v + 1];
    for (; e + 4 <= end; e += 4) {
        float x0 = hc[(size_t)perm[e] * 4];
        float x1 = hc[(size_t)perm[e + 1] * 4];
        float x2 = hc[(size_t)perm[e + 2] * 4];
        float x3 = hc[(size_t)perm[e + 3] * 4];
        acc += (x0 + x1) + (x2 + x3);
    }
    for (; e < end; ++e) acc += hc[(size_t)perm[e] * 4];
    out[(size_t)v * 4 + c] = acc * dinv[v] + b[c];
}

extern "C" void kernel_launch(void* const* d_in, const int* in_sizes, int n_in,
                              void* d_out, int out_size, void* d_ws, size_t ws_size,
                              hipStream_t stream) {
    const float* x  = (const float*)d_in[0];
    const int* ei   = (const int*)d_in[1];
    const float* W0 = (const float*)d_in[2];
    const float* b0 = (const float*)d_in[3];
    const float* W1 = (const float*)d_in[4];
    const float* b1 = (const float*)d_in[5];
    const float* W2 = (const float*)d_in[6];
    const float* b2 = (const float*)d_in[7];
    float* out = (float*)d_out;

    const int N = in_sizes[0] / 64;
    const int E = in_sizes[1] / 2;
    const int* src = ei;
    const int* dst = ei + E;
    const int es = (E + NCHUNK - 1) / NCHUNK;   // edges per chunk

    // workspace layout, 256B-aligned slabs
    char* base = (char*)d_ws;
    size_t off = 0;
    auto alloc = [&](size_t bytes) { size_t o = off; off = (off + bytes + 255) & ~(size_t)255; return o; };
    unsigned int*   histw  = (unsigned int*)(base + alloc((size_t)NCHUNK * NPAD));  // u8[C][NPAD]
    unsigned char*  rank   = (unsigned char*)(base + alloc((size_t)E));
    unsigned short* deg16  = (unsigned short*)(base + alloc((size_t)NPAD * 2));
    float*          dinv   = (float*)(base + alloc((size_t)NPAD * 4));
    int*            rowptr = (int*)(base + alloc((size_t)(NPAD + 1) * 4));
    int*            bsum   = (int*)(base + alloc(1024));
    int*            perm   = (int*)(base + alloc((size_t)E * 4));
    float*          bufA   = (float*)(base + alloc((size_t)N * 64 * 4));
    float*          bufB   = (float*)(base + alloc((size_t)N * 64 * 4));

    const int nb_N = (N + 255) / 256;   // 196
    const int nb_E = (E + 255) / 256;

    // ---- CSR build + normalization (no global atomics) ----
    k_hist<<<NCHUNK, 1024, NW8 * sizeof(unsigned int), stream>>>(dst, histw, rank, E, es);
    k_chscan<<<NPAD / 256, 256, 0, stream>>>((unsigned char*)histw, dinv, deg16, bsum, N);
    k_scan3<<<nb_N, 256, 0, stream>>>(deg16, bsum, rowptr, N, nb_N);
    k_place<<<nb_E, 256, 0, stream>>>(src, dst, rowptr, rank, (const unsigned char*)histw, perm, E, es);

    // ---- layer 0 ----
    k_gemm64<<<(N + 15) / 16, 256, 0, stream>>>(x, W0, dinv, bufA, N);
    k_gather64<<<(N + 3) / 4, 256, 0, stream>>>(bufA, dinv, rowptr, perm, b0, bufB, N, 1);

    // ---- layer 1 ----
    k_gemm64<<<(N + 15) / 16, 256, 0, stream>>>(bufB, W1, dinv, bufA, N);
    k_gather64<<<(N + 3) / 4, 256, 0, stream>>>(bufA, dinv, rowptr, perm, b1, bufB, N, 1);

    // ---- layer 2 (d_out = 4) ----
    k_gemm4<<<nb_N, 256, 0, stream>>>(bufB, W2, dinv, bufA, N);
    k_gather4<<<(N * 4 + 255) / 256, 256, 0, stream>>>(bufA, dinv, rowptr, perm, b2, out, N);
}